// Round 13
// baseline (14.882 us; speedup 1.0000x reference)
//
#include <hip/hip_runtime.h>
#include <math.h>

// Problem constants (from reference)
#define BS 4
#define S 4096
#define H 32
#define KVH 8
#define HD 128
#define G 4            // H / KVH
#define WIN 1024
#define SCALE 0.08838834764831843f  // 1/sqrt(128)

// Flash-decoding split: 16 splits x 64 positions, processed as 2 sub-chunks of 32
// with double-buffered K (pipelined: K1 fetch rides under sub-chunk-0 compute).
#define NSPLIT 16
#define CHUNK 64
#define SUB 32
#define PSTRIDE 132            // 128 out + m + l + 2 pad (keeps float4 alignment)

// async global->LDS, 16B per lane, wave-uniform LDS base (+lane*16 by HW)
#define GLOAD_LDS16(gsrc, ldst) \
    __builtin_amdgcn_global_load_lds( \
        (const __attribute__((address_space(1))) void*)(gsrc), \
        (__attribute__((address_space(3))) void*)(ldst), 16, 0, 0)

// wave-uniform float broadcast from a compile-time lane (VALU pipe, no DS)
#define READLANE_F(x, l) \
    __uint_as_float(__builtin_amdgcn_readlane(__float_as_uint(x), (l)))

// ---- DPP cross-lane reductions (VALU pipe, not DS) ----
template <int CTRL>
__device__ __forceinline__ float dpp_mov(float x) {
    return __int_as_float(__builtin_amdgcn_update_dpp(
        0, __float_as_int(x), CTRL, 0xF, 0xF, true));
}
__device__ __forceinline__ float red_add16(float d) {
    d += dpp_mov<0xB1>(d);
    d += dpp_mov<0x4E>(d);
    d += dpp_mov<0x124>(d);
    d += dpp_mov<0x128>(d);
    return d;   // all 16 lanes of each row hold the row sum
}
__device__ __forceinline__ float red_max16(float d) {
    d = fmaxf(d, dpp_mov<0xB1>(d));
    d = fmaxf(d, dpp_mov<0x4E>(d));
    d = fmaxf(d, dpp_mov<0x124>(d));
    d = fmaxf(d, dpp_mov<0x128>(d));
    return d;
}

// Kernel 1: one block per (b, kvh, split). CHUNK=64 as two pipelined sub-chunks:
// stage K0 -> barrier -> {issue K1 stage + V0 regs} -> QK0/sm0/PV0 -> barrier
// -> {issue V1 regs} -> QK1/sm1/PV1 -> online-softmax merge -> one record.
// Only K0's fetch is chip-wide exposed (8.4 MB vs 33.6 MB).
__global__ __launch_bounds__(256) void attn_split_kernel(
    const float* __restrict__ q, const float* __restrict__ k,
    const float* __restrict__ v, const float* __restrict__ mask,
    const int* __restrict__ start_positions, float* __restrict__ ws)
{
    const int blk   = blockIdx.x;
    const int split = blk % NSPLIT;
    const int kvh   = (blk / NSPLIT) % KVH;
    const int b     = blk / (NSPLIT * KVH);
    const int tid   = threadIdx.x;
    const int g     = tid >> 6;    // wave id == head-in-group
    const int lane  = tid & 63;
    const int grp   = lane >> 4;   // 0..3: position group (QK)
    const int l16   = lane & 15;   // dim slot within group
    const int h     = kvh * G + g;
    const int half  = lane >> 5;
    const int l32   = lane & 31;

    const int p = start_positions[b];             // last valid position
    const int base_pos = p - WIN + 1 + split * CHUNK;

    __shared__ float kbuf[2][SUB][HD];  // 2 x 16 KB
    __shared__ float sc[G][SUB];        // per-wave raw-dot scratch

    const size_t kv_base = (size_t)b * S * (KVH * HD) + (size_t)kvh * HD;
    const int srow = lane >> 5;          // row within 1KB stripe
    const int scol = (lane & 31) * 4;    // float col within row

    // ---- stage K sub-chunk into kbuf[buf]: 16 stripes of 1KB, 4 per wave ----
    auto stageK = [&](int buf, int sub_base) {
        #pragma unroll
        for (int i = 0; i < 4; ++i) {
            const int st  = g * 4 + i;       // stripe 0..15
            const int r   = st * 2 + srow;   // row within sub-chunk
            const int pos = sub_base + r;
            const int row = (pos == p) ? (S - 1) : (pos < 0 ? 0 : pos);
            GLOAD_LDS16(k + kv_base + (size_t)row * (KVH * HD) + scol,
                        (char*)&kbuf[buf][0][0] + st * 1024);
        }
    };

    stageK(0, base_pos);

    // masks for both sub-chunks (off the critical path)
    const int lpos0 = base_pos + l32;
    const int lpos1 = base_pos + SUB + l32;
    const float msk0 = (lpos0 >= 0) ? mask[(size_t)b * S + lpos0] : 0.f;
    const float msk1 = (lpos1 >= 0) ? mask[(size_t)b * S + lpos1] : 0.f;

    // q fragment: dims [l16*8, l16*8+8) of this head's last token
    const float* qptr = q + (((size_t)b * S + (S - 1)) * H + h) * HD + l16 * 8;
    const float4 qa = *(const float4*)(qptr);
    const float4 qb = *(const float4*)(qptr + 4);

    __syncthreads();   // K0 staged

    // ---- issue K1 stage: fetch rides under sub-chunk-0 compute ----
    stageK(1, base_pos + SUB);

    // ---- issue V0 register loads: overlap QK0+softmax0 ----
    float4 v0[SUB / 2];
    #pragma unroll
    for (int it = 0; it < SUB / 2; ++it) {
        const int pos = base_pos + it * 2 + half;
        const int row = (pos == p) ? (S - 1) : (pos < 0 ? 0 : pos);
        v0[it] = *(const float4*)(v + kv_base + (size_t)row * (KVH * HD) + l32 * 4);
    }
    asm volatile("" ::: "memory");   // pin V0 issue before QK0

    // ---- QK0 from kbuf[0] ----
    #pragma unroll
    for (int it = 0; it < SUB / 4; ++it) {
        const int jj = it * 4 + grp;
        const float4 ka = *(const float4*)(&kbuf[0][jj][l16 * 8]);
        const float4 kb = *(const float4*)(&kbuf[0][jj][l16 * 8 + 4]);
        float d = qa.x * ka.x + qa.y * ka.y + qa.z * ka.z + qa.w * ka.w
                + qb.x * kb.x + qb.y * kb.y + qb.z * kb.z + qb.w * kb.w;
        d = red_add16(d);
        if (l16 == 0) sc[g][jj] = d;
    }

    // ---- softmax0 over 32 positions ----
    float s0 = sc[g][l32] * SCALE + msk0;
    if (lpos0 < 0) s0 = -1e30f;
    float m0 = red_max16(s0);
    m0 = fmaxf(m0, __shfl_xor(m0, 16, 64));
    const float e0 = __expf(s0 - m0);
    float l0 = red_add16(e0);
    l0 += __shfl_xor(l0, 16, 64);

    // ---- PV0 from registers ----
    float4 oa = make_float4(0.f, 0.f, 0.f, 0.f);
    #pragma unroll
    for (int it = 0; it < SUB / 2; ++it) {
        const float ea = READLANE_F(e0, it * 2);
        const float eb = READLANE_F(e0, it * 2 + 1);
        const float e  = half ? eb : ea;
        oa.x += e * v0[it].x; oa.y += e * v0[it].y;
        oa.z += e * v0[it].z; oa.w += e * v0[it].w;
    }

    __syncthreads();   // K1 staged

    // ---- issue V1 register loads: overlap QK1+softmax1 ----
    float4 v1[SUB / 2];
    #pragma unroll
    for (int it = 0; it < SUB / 2; ++it) {
        const int pos = base_pos + SUB + it * 2 + half;
        const int row = (pos == p) ? (S - 1) : (pos < 0 ? 0 : pos);
        v1[it] = *(const float4*)(v + kv_base + (size_t)row * (KVH * HD) + l32 * 4);
    }
    asm volatile("" ::: "memory");   // pin V1 issue before QK1

    // ---- QK1 from kbuf[1] ----
    #pragma unroll
    for (int it = 0; it < SUB / 4; ++it) {
        const int jj = it * 4 + grp;
        const float4 ka = *(const float4*)(&kbuf[1][jj][l16 * 8]);
        const float4 kb = *(const float4*)(&kbuf[1][jj][l16 * 8 + 4]);
        float d = qa.x * ka.x + qa.y * ka.y + qa.z * ka.z + qa.w * ka.w
                + qb.x * kb.x + qb.y * kb.y + qb.z * kb.z + qb.w * kb.w;
        d = red_add16(d);
        if (l16 == 0) sc[g][jj] = d;
    }

    // ---- softmax1 ----
    float s1 = sc[g][l32] * SCALE + msk1;
    if (lpos1 < 0) s1 = -1e30f;
    float m1 = red_max16(s1);
    m1 = fmaxf(m1, __shfl_xor(m1, 16, 64));
    const float e1 = __expf(s1 - m1);
    float l1 = red_add16(e1);
    l1 += __shfl_xor(l1, 16, 64);

    // ---- PV1 from registers ----
    float4 ob = make_float4(0.f, 0.f, 0.f, 0.f);
    #pragma unroll
    for (int it = 0; it < SUB / 2; ++it) {
        const float ea = READLANE_F(e1, it * 2);
        const float eb = READLANE_F(e1, it * 2 + 1);
        const float e  = half ? eb : ea;
        ob.x += e * v1[it].x; ob.y += e * v1[it].y;
        ob.z += e * v1[it].z; ob.w += e * v1[it].w;
    }

    // ---- online-softmax merge of the two sub-chunks ----
    const float mm = fmaxf(m0, m1);
    const float w0 = __expf(m0 - mm);
    const float w1 = __expf(m1 - mm);
    const float lsum = l0 * w0 + l1 * w1;
    float4 o4;
    o4.x = oa.x * w0 + ob.x * w1;
    o4.y = oa.y * w0 + ob.y * w1;
    o4.z = oa.z * w0 + ob.z * w1;
    o4.w = oa.w * w0 + ob.w * w1;

    o4.x += __shfl_xor(o4.x, 32, 64);
    o4.y += __shfl_xor(o4.y, 32, 64);
    o4.z += __shfl_xor(o4.z, 32, 64);
    o4.w += __shfl_xor(o4.w, 32, 64);

    const size_t widx = ((((size_t)b * KVH + kvh) * G + g) * NSPLIT + split) * (size_t)PSTRIDE;
    if (lane < 32) {
        *(float4*)(ws + widx + 4 * l32) = o4;
        if (lane == 0) {
            float2 ml2; ml2.x = mm; ml2.y = lsum;
            *(float2*)(ws + widx + 128) = ml2;
        }
    }
}

// Kernel 2: one 256-thread block per (b, h). 4 waves x 4 splits each, two-phase
// LDS merge (block max, then weighted sums). (m,l) read as one float2.
__global__ __launch_bounds__(256) void attn_reduce_kernel(
    const float* __restrict__ ws, const float* __restrict__ sink,
    float* __restrict__ out)
{
    const int blk = blockIdx.x;    // b*H + h
    const int h = blk % H;
    const int b = blk / H;
    const int kvh = h / G;
    const int g = h % G;
    const int tid = threadIdx.x;
    const int w = tid >> 6;        // wave 0..3: handles splits [w*4, w*4+4)
    const int lane = tid & 63;

    const size_t base = ((((size_t)b * KVH + kvh) * G + g) * (size_t)NSPLIT) * (size_t)PSTRIDE;

    __shared__ float red_m[4];
    __shared__ float red_d[4];
    __shared__ float red_o[4][HD];

    const float sk = sink[h];

    // phase 1: per-wave max over its 4 partial maxima ((m,l) as float2)
    float2 ml[4];
    float Mw = -1e30f;
    #pragma unroll
    for (int i = 0; i < 4; ++i) {
        ml[i] = *(const float2*)(ws + base + (size_t)(w * 4 + i) * PSTRIDE + 128);
        Mw = fmaxf(Mw, ml[i].x);
    }
    if (lane == 0) red_m[w] = Mw;
    __syncthreads();
    float M = fmaxf(fmaxf(red_m[0], red_m[1]), fmaxf(red_m[2], red_m[3]));
    M = fmaxf(M, sk);

    // phase 2: per-wave weighted sums over its 4 records
    float D = 0.f, ax = 0.f, ay = 0.f;
    #pragma unroll
    for (int i = 0; i < 4; ++i) {
        const size_t rec = base + (size_t)(w * 4 + i) * PSTRIDE;
        const float wgt = __expf(ml[i].x - M);
        D += wgt * ml[i].y;
        const float2 o2 = *(const float2*)(ws + rec + 2 * lane);
        ax += wgt * o2.x;
        ay += wgt * o2.y;
    }
    if (lane == 0) red_d[w] = D;
    red_o[w][2 * lane]     = ax;
    red_o[w][2 * lane + 1] = ay;
    __syncthreads();

    // final combine + write by wave 0
    if (w == 0) {
        const float Dt = red_d[0] + red_d[1] + red_d[2] + red_d[3] + __expf(sk - M);
        const float ox = red_o[0][2 * lane] + red_o[1][2 * lane]
                       + red_o[2][2 * lane] + red_o[3][2 * lane];
        const float oy = red_o[0][2 * lane + 1] + red_o[1][2 * lane + 1]
                       + red_o[2][2 * lane + 1] + red_o[3][2 * lane + 1];
        const float invD = 1.f / Dt;
        float2 r; r.x = ox * invD; r.y = oy * invD;
        *(float2*)(out + ((size_t)b * H + h) * HD + 2 * lane) = r;
    }
}

extern "C" void kernel_launch(void* const* d_in, const int* in_sizes, int n_in,
                              void* d_out, int out_size, void* d_ws, size_t ws_size,
                              hipStream_t stream) {
    const float* q    = (const float*)d_in[0];
    const float* k    = (const float*)d_in[1];
    const float* v    = (const float*)d_in[2];
    // d_in[3] k_cache, d_in[4] v_cache, d_in[7] seq_block_ids: not needed for the
    // output — scatter-then-gather with injective page ids is the identity, and the
    // last-token overwrite is handled by the row remap (pos==p -> S-1).
    const float* mask = (const float*)d_in[5];
    const float* sink = (const float*)d_in[6];
    const int* start_positions = (const int*)d_in[8];
    float* out = (float*)d_out;
    float* ws  = (float*)d_ws;   // needs BS*KVH*G*NSPLIT*PSTRIDE*4 B ~= 1.1 MB

    attn_split_kernel<<<BS * KVH * NSPLIT, 256, 0, stream>>>(q, k, v, mask, start_positions, ws);
    attn_reduce_kernel<<<BS * H, 256, 0, stream>>>(ws, sink, out);
}